// Round 1
// baseline (31487.109 us; speedup 1.0000x reference)
//
#include <hip/hip_runtime.h>

#define BLK 256

// ---------------------------------------------------------------------------
// Occupancy compaction: list of linear indices (b*DHW + sp) where mask > 0.
// ---------------------------------------------------------------------------
__global__ void compact_k(const float* __restrict__ m, int* __restrict__ list,
                          int* __restrict__ cnt, int total) {
  int i = blockIdx.x * BLK + threadIdx.x;
  if (i >= total) return;
  if (m[i] > 0.f) { int p = atomicAdd(cnt, 1); list[p] = i; }
}

// 2x2x2 max-pool of mask + compaction of the pooled mask.
__global__ void downmask_k(const float* __restrict__ mi, float* __restrict__ mo,
                           int* __restrict__ list, int* __restrict__ cnt,
                           int Do, int Ho, int Wo) {
  int DHWo = Do * Ho * Wo;
  int total = 2 * DHWo;
  int i = blockIdx.x * BLK + threadIdx.x;
  if (i >= total) return;
  int b = i / DHWo, sp = i - b * DHWo;
  int z = sp / (Ho * Wo); int r = sp - z * Ho * Wo; int y = r / Wo; int x = r - y * Wo;
  int Hi = 2 * Ho, Wi = 2 * Wo;
  const float* mb = mi + b * (2 * Do) * Hi * Wi;
  float mx = 0.f;
  for (int dz = 0; dz < 2; dz++)
    for (int dy = 0; dy < 2; dy++)
      for (int dx = 0; dx < 2; dx++)
        mx = fmaxf(mx, mb[((2 * z + dz) * Hi + 2 * y + dy) * Wi + 2 * x + dx]);
  mo[i] = mx;
  if (mx > 0.f) { int p = atomicAdd(cnt, 1); list[p] = i; }
}

// ---------------------------------------------------------------------------
// Sparse gather convs: thread = (voxel-from-list, cout); input is dense with
// guaranteed zeros at unoccupied sites. Grid-stride, guarded by device count.
// ---------------------------------------------------------------------------
template <int CIN>
__global__ void conv3_k(const float* __restrict__ in, const float* __restrict__ w,
                        float* __restrict__ out, const int* __restrict__ list,
                        const int* __restrict__ cntp, int COUT,
                        int D, int H, int Wd) {
  int DHW = D * H * Wd;
  int n = *cntp;
  int nwork = n * COUT;
  for (int t = blockIdx.x * BLK + threadIdx.x; t < nwork; t += gridDim.x * BLK) {
    int vox = t / COUT, co = t - vox * COUT;
    int idx = list[vox];
    int b = idx / DHW, sp = idx - b * DHW;
    int z = sp / (H * Wd); int r2 = sp - z * H * Wd; int y = r2 / Wd; int x = r2 - y * Wd;
    const float* inb = in + b * CIN * DHW;
    const float* wco = w + co * CIN * 27;
    float acc = 0.f;
    #pragma unroll
    for (int dz = 0; dz < 3; dz++) {
      int zz = z + dz - 1; if ((unsigned)zz >= (unsigned)D) continue;
      #pragma unroll
      for (int dy = 0; dy < 3; dy++) {
        int yy = y + dy - 1; if ((unsigned)yy >= (unsigned)H) continue;
        #pragma unroll
        for (int dx = 0; dx < 3; dx++) {
          int xx = x + dx - 1; if ((unsigned)xx >= (unsigned)Wd) continue;
          int spn = (zz * H + yy) * Wd + xx;
          const float* ip = inb + spn;
          const float* wp = wco + (dz * 3 + dy) * 3 + dx;
          #pragma unroll 8
          for (int ci = 0; ci < CIN; ci++)
            acc += ip[ci * DHW] * wp[ci * 27];
        }
      }
    }
    out[(b * COUT + co) * DHW + sp] = acc;
  }
}

template <int CIN>
__global__ void conv2s2_k(const float* __restrict__ in, const float* __restrict__ w,
                          float* __restrict__ out, const int* __restrict__ list,
                          const int* __restrict__ cntp, int COUT,
                          int Do, int Ho, int Wo) {
  int DHWo = Do * Ho * Wo;
  int Hi = 2 * Ho, Wi = 2 * Wo;
  int DHWi = 8 * DHWo;
  int n = *cntp;
  int nwork = n * COUT;
  for (int t = blockIdx.x * BLK + threadIdx.x; t < nwork; t += gridDim.x * BLK) {
    int vox = t / COUT, co = t - vox * COUT;
    int idx = list[vox];
    int b = idx / DHWo, sp = idx - b * DHWo;
    int z = sp / (Ho * Wo); int r2 = sp - z * Ho * Wo; int y = r2 / Wo; int x = r2 - y * Wo;
    const float* inb = in + b * CIN * DHWi;
    const float* wco = w + co * CIN * 8;
    float acc = 0.f;
    #pragma unroll
    for (int dz = 0; dz < 2; dz++)
      #pragma unroll
      for (int dy = 0; dy < 2; dy++)
        #pragma unroll
        for (int dx = 0; dx < 2; dx++) {
          int spn = ((2 * z + dz) * Hi + 2 * y + dy) * Wi + 2 * x + dx;
          const float* ip = inb + spn;
          const float* wp = wco + (dz * 2 + dy) * 2 + dx;
          #pragma unroll 8
          for (int ci = 0; ci < CIN; ci++)
            acc += ip[ci * DHWi] * wp[ci * 8];
        }
    out[(b * COUT + co) * DHWo + sp] = acc;
  }
}

template <int CIN>
__global__ void conv1_k(const float* __restrict__ in, const float* __restrict__ w,
                        float* __restrict__ out, const int* __restrict__ list,
                        const int* __restrict__ cntp, int COUT, int DHW) {
  int n = *cntp;
  int nwork = n * COUT;
  for (int t = blockIdx.x * BLK + threadIdx.x; t < nwork; t += gridDim.x * BLK) {
    int vox = t / COUT, co = t - vox * COUT;
    int idx = list[vox];
    int b = idx / DHW, sp = idx - b * DHW;
    const float* inb = in + b * CIN * DHW + sp;
    const float* wco = w + co * CIN;
    float acc = 0.f;
    #pragma unroll 8
    for (int ci = 0; ci < CIN; ci++)
      acc += inb[ci * DHW] * wco[ci];
    out[(b * COUT + co) * DHW + sp] = acc;
  }
}

// ---------------------------------------------------------------------------
// Masked BN statistics over compacted list. slot layout (floats):
// [0..C) sum | [256..256+C) sumsq | [512..512+C) a=scale | [768..768+C) b=-mean*scale
// ---------------------------------------------------------------------------
__global__ void reduce_stats_k(const float* __restrict__ raw, const int* __restrict__ list,
                               const int* __restrict__ cntp, int C, int DHW,
                               float* __restrict__ slot) {
  int c = blockIdx.y;
  int n = *cntp;
  float s = 0.f, s2 = 0.f;
  for (int i = blockIdx.x * BLK + threadIdx.x; i < n; i += gridDim.x * BLK) {
    int idx = list[i];
    int b = idx / DHW, sp = idx - b * DHW;
    float v = raw[(b * C + c) * DHW + sp];
    s += v; s2 += v * v;
  }
  __shared__ float sh[BLK], sh2[BLK];
  int tid = threadIdx.x;
  sh[tid] = s; sh2[tid] = s2;
  __syncthreads();
  for (int o = BLK / 2; o > 0; o >>= 1) {
    if (tid < o) { sh[tid] += sh[tid + o]; sh2[tid] += sh2[tid + o]; }
    __syncthreads();
  }
  if (tid == 0) {
    atomicAdd(&slot[c], sh[0]);
    atomicAdd(&slot[256 + c], sh2[0]);
  }
}

__global__ void finalize_k(float* __restrict__ slot, const int* __restrict__ cntp, int C) {
  int c = threadIdx.x;
  if (c >= C) return;
  float cnt = fmaxf((float)(*cntp), 1.f);
  float mean = slot[c] / cnt;
  float var = fmaxf(slot[256 + c] / cnt - mean * mean, 0.f);
  float sc = rsqrtf(var + 1e-5f);
  slot[512 + c] = sc;
  slot[768 + c] = -mean * sc;
}

// ---------------------------------------------------------------------------
// Dense BN+ReLU apply. mode 0: relu(bn(raw)); 1: relu(bn(raw)+bn2(aux));
// 2: relu(bn(raw)+aux). Writes zeros where mask==0 (output is dense-valid).
// Safe in-place (each thread reads/writes only its own element).
// ---------------------------------------------------------------------------
__global__ void apply_k(const float* raw, const float* __restrict__ mask,
                        const float* __restrict__ slot, const float* aux,
                        const float* __restrict__ slot2, float* out,
                        int C, int DHW, int total, int mode) {
  for (int i = blockIdx.x * BLK + threadIdx.x; i < total; i += gridDim.x * BLK) {
    int sp = i % DHW;
    int bc = i / DHW;
    int c = bc % C;
    int b = bc / C;
    float m = mask[b * DHW + sp];
    float v = 0.f;
    if (m > 0.f) {
      v = raw[i] * slot[512 + c] + slot[768 + c];
      if (mode == 1) v += aux[i] * slot2[512 + c] + slot2[768 + c];
      else if (mode == 2) v += aux[i];
      v = fmaxf(v, 0.f);
    }
    out[i] = v;
  }
}

// ---------------------------------------------------------------------------
// Host-side helpers
// ---------------------------------------------------------------------------
struct Dims { int D, H, W; };

static inline int conv_blocks(int DHW, int COUT) {
  long w = (long)2 * DHW * COUT / BLK;
  if (w < 1) w = 1;
  if (w > 2048) w = 2048;
  return (int)w;
}

static void conv3_launch(const float* in, const float* w, float* out, const int* list,
                         const int* cnt, int CIN, int COUT, Dims d, hipStream_t s) {
  int g = conv_blocks(d.D * d.H * d.W, COUT);
  switch (CIN) {
    case 3:   conv3_k<3><<<g, BLK, 0, s>>>(in, w, out, list, cnt, COUT, d.D, d.H, d.W); break;
    case 32:  conv3_k<32><<<g, BLK, 0, s>>>(in, w, out, list, cnt, COUT, d.D, d.H, d.W); break;
    case 64:  conv3_k<64><<<g, BLK, 0, s>>>(in, w, out, list, cnt, COUT, d.D, d.H, d.W); break;
    case 128: conv3_k<128><<<g, BLK, 0, s>>>(in, w, out, list, cnt, COUT, d.D, d.H, d.W); break;
    case 256: conv3_k<256><<<g, BLK, 0, s>>>(in, w, out, list, cnt, COUT, d.D, d.H, d.W); break;
  }
}

static void conv2_launch(const float* in, const float* w, float* out, const int* list,
                         const int* cnt, int CIN, int COUT, Dims d, hipStream_t s) {
  int g = conv_blocks(d.D * d.H * d.W, COUT);
  switch (CIN) {
    case 32:  conv2s2_k<32><<<g, BLK, 0, s>>>(in, w, out, list, cnt, COUT, d.D, d.H, d.W); break;
    case 64:  conv2s2_k<64><<<g, BLK, 0, s>>>(in, w, out, list, cnt, COUT, d.D, d.H, d.W); break;
    case 128: conv2s2_k<128><<<g, BLK, 0, s>>>(in, w, out, list, cnt, COUT, d.D, d.H, d.W); break;
  }
}

static void conv1_launch(const float* in, const float* w, float* out, const int* list,
                         const int* cnt, int CIN, int COUT, Dims d, hipStream_t s) {
  int DHW = d.D * d.H * d.W;
  int g = conv_blocks(DHW, COUT);
  switch (CIN) {
    case 32:  conv1_k<32><<<g, BLK, 0, s>>>(in, w, out, list, cnt, COUT, DHW); break;
    case 64:  conv1_k<64><<<g, BLK, 0, s>>>(in, w, out, list, cnt, COUT, DHW); break;
    case 128: conv1_k<128><<<g, BLK, 0, s>>>(in, w, out, list, cnt, COUT, DHW); break;
  }
}

static void run_bn(const float* raw, const int* list, const int* cnt, int C, int DHW,
                   float* slot, hipStream_t s) {
  reduce_stats_k<<<dim3(16, C), BLK, 0, s>>>(raw, list, cnt, C, DHW, slot);
  finalize_k<<<1, 256, 0, s>>>(slot, cnt, C);
}

static void run_apply(const float* raw, const float* mask, const float* slot,
                      const float* aux, const float* slot2, float* out,
                      int C, int DHW, int mode, hipStream_t s) {
  int total = 2 * C * DHW;
  int blocks = (total + BLK - 1) / BLK;
  if (blocks > 4096) blocks = 4096;
  apply_k<<<blocks, BLK, 0, s>>>(raw, mask, slot, aux, slot2, out, C, DHW, total, mode);
}

#define SLOT_FLOATS 2097152  // 8 MiB per stage buffer slot

// One encoder stage: downsample conv + 2 residual blocks. Returns in bank slot 3.
static void run_stage(const float* pin, int Cp, int Co,
                      const float* wd, const float* wa1, const float* wb1, const float* wsk,
                      const float* wa2, const float* wb2,
                      const float* mprev, float* mcur, int* lcur, int* ccur,
                      Dims dc, float* bank, float* stats, int& slot,
                      float* final_out, hipStream_t s) {
  int DHW = dc.D * dc.H * dc.W;
  int tot = 2 * DHW;
  downmask_k<<<(tot + BLK - 1) / BLK, BLK, 0, s>>>(mprev, mcur, lcur, ccur, dc.D, dc.H, dc.W);

  float* R0 = bank + 0 * SLOT_FLOATS;
  float* R1 = bank + 1 * SLOT_FLOATS;
  float* R2 = bank + 2 * SLOT_FLOATS;
  float* R3 = bank + 3 * SLOT_FLOATS;

  // downsample conv block: Cp -> Cp, ks=2, s=2
  conv2_launch(pin, wd, R0, lcur, ccur, Cp, Cp, dc, s);
  float* sl = stats + (slot++) * 1024;
  run_bn(R0, lcur, ccur, Cp, DHW, sl, s);
  run_apply(R0, mcur, sl, R0, sl, R0, Cp, DHW, 0, s);   // x2 = R0

  // res block 1
  conv3_launch(R0, wa1, R1, lcur, ccur, Cp, Co, dc, s);
  sl = stats + (slot++) * 1024;
  run_bn(R1, lcur, ccur, Co, DHW, sl, s);
  run_apply(R1, mcur, sl, R1, sl, R1, Co, DHW, 0, s);   // t = R1
  conv3_launch(R1, wb1, R2, lcur, ccur, Co, Co, dc, s);
  float* slB = stats + (slot++) * 1024;
  run_bn(R2, lcur, ccur, Co, DHW, slB, s);
  if (wsk) {
    conv1_launch(R0, wsk, R3, lcur, ccur, Cp, Co, dc, s);
    float* slS = stats + (slot++) * 1024;
    run_bn(R3, lcur, ccur, Co, DHW, slS, s);
    run_apply(R2, mcur, slB, R3, slS, R2, Co, DHW, 1, s);  // res1 = R2
  } else {
    run_apply(R2, mcur, slB, R0, slB, R2, Co, DHW, 2, s);  // identity skip
  }

  // res block 2 (identity skip)
  conv3_launch(R2, wa2, R1, lcur, ccur, Co, Co, dc, s);
  sl = stats + (slot++) * 1024;
  run_bn(R1, lcur, ccur, Co, DHW, sl, s);
  run_apply(R1, mcur, sl, R1, sl, R1, Co, DHW, 0, s);
  conv3_launch(R1, wb2, R3, lcur, ccur, Co, Co, dc, s);
  slB = stats + (slot++) * 1024;
  run_bn(R3, lcur, ccur, Co, DHW, slB, s);
  run_apply(R3, mcur, slB, R2, slB, final_out ? final_out : R3, Co, DHW, 2, s);
}

extern "C" void kernel_launch(void* const* d_in, const int* in_sizes, int n_in,
                              void* d_out, int out_size, void* d_ws, size_t ws_size,
                              hipStream_t stream) {
  const float* feats = (const float*)d_in[0];
  const float* mask0 = (const float*)d_in[1];
  auto Wp = [&](int i) { return (const float*)d_in[i]; };

  char* wsb = (char*)d_ws;
  float* A  = (float*)wsb;                       // 64 MiB: 8 stage slots / full-res buf
  float* Bb = (float*)(wsb + 67108864);          // 64 MiB
  char* aux = wsb + 134217728;
  float* m1 = (float*)(aux + 0);                 // 2*32^3*4   = 262144
  float* m2 = (float*)(aux + 262144);            // 2*16^3*4   = 32768
  float* m3 = (float*)(aux + 294912);            // 2*8^3*4    = 4096
  float* m4 = (float*)(aux + 299008);            // 2*4^3*4    = 512
  int* l0   = (int*)(aux + 299520);              // 2*64^3*4   = 2097152
  int* l1   = (int*)(aux + 2396672);             // 262144
  int* l2   = (int*)(aux + 2658816);             // 32768
  int* l3   = (int*)(aux + 2691584);             // 4096
  int* l4   = (int*)(aux + 2695680);             // 512
  float* stats = (float*)(aux + 2696192);        // 32 slots * 1024 f = 131072 B
  int* cnts = (int*)(aux + 2827264);             // 5 counters (zeroed with stats)

  // zero stats accumulators + counters every call (ws is not re-poisoned)
  hipMemsetAsync(stats, 0, 131072 + 128, stream);

  Dims d0{64, 64, 64}, d1{32, 32, 32}, d2{16, 16, 16}, d3{8, 8, 8}, d4{4, 4, 4};
  int slot = 0;

  // level-0 occupancy list
  compact_k<<<(2 * 262144 + BLK - 1) / BLK, BLK, 0, stream>>>(mask0, l0, cnts + 0, 2 * 262144);

  // cbr1: conv3 3->32, bn(mask0), relu   (feats is already masked)
  conv3_launch(feats, Wp(2), A, l0, cnts + 0, 3, 32, d0, stream);
  float* sl = stats + (slot++) * 1024;
  run_bn(A, l0, cnts + 0, 32, 262144, sl, stream);
  run_apply(A, mask0, sl, A, sl, A, 32, 262144, 0, stream);

  // cbr2: conv3 32->32
  conv3_launch(A, Wp(3), Bb, l0, cnts + 0, 32, 32, d0, stream);
  sl = stats + (slot++) * 1024;
  run_bn(Bb, l0, cnts + 0, 32, 262144, sl, stream);
  run_apply(Bb, mask0, sl, Bb, sl, Bb, 32, 262144, 0, stream);

  // stage 1: 32->32, identity skip; buffers in A (input Bb)
  run_stage(Bb, 32, 32, Wp(4), Wp(5), Wp(6), nullptr, Wp(7), Wp(8),
            mask0, m1, l1, cnts + 1, d1, A, stats, slot, nullptr, stream);
  float* s1out = A + 3 * SLOT_FLOATS;

  // stage 2: 32->64, conv skip; buffers in Bb (input in A)
  run_stage(s1out, 32, 64, Wp(9), Wp(10), Wp(11), Wp(12), Wp(13), Wp(14),
            m1, m2, l2, cnts + 2, d2, Bb, stats, slot, nullptr, stream);
  float* s2out = Bb + 3 * SLOT_FLOATS;

  // stage 3: 64->128, conv skip; buffers in A (input in Bb)
  run_stage(s2out, 64, 128, Wp(15), Wp(16), Wp(17), Wp(18), Wp(19), Wp(20),
            m2, m3, l3, cnts + 3, d3, A, stats, slot, nullptr, stream);
  float* s3out = A + 3 * SLOT_FLOATS;

  // stage 4: 128->256, conv skip; buffers in Bb (input in A); final -> d_out
  run_stage(s3out, 128, 256, Wp(21), Wp(22), Wp(23), Wp(24), Wp(25), Wp(26),
            m3, m4, l4, cnts + 4, d4, Bb, stats, slot, (float*)d_out, stream);
}

// Round 2
// 3262.626 us; speedup vs baseline: 9.6508x; 9.6508x over previous
//
#include <hip/hip_runtime.h>

#define BLK 256

// ---------------------------------------------------------------------------
// Level-0 map build: map[densesite] = compact idx or -1; list[compact] = dense.
// ---------------------------------------------------------------------------
__global__ void build_map0_k(const float* __restrict__ m, int* __restrict__ map,
                             int* __restrict__ list, int* __restrict__ cnt,
                             int total, int cap) {
  int i = blockIdx.x * BLK + threadIdx.x;
  if (i >= total) return;
  if (m[i] > 0.f) {
    int p = atomicAdd(cnt, 1);
    if (p < cap) { list[p] = i; map[i] = p; } else map[i] = -1;
  } else map[i] = -1;
}

// Coarse level occupancy from previous level's map (2x2x2 any-occupied).
__global__ void downmap_k(const int* __restrict__ mapp, int* __restrict__ mapc,
                          int* __restrict__ listc, int* __restrict__ cntc,
                          int Do, int Ho, int Wo) {
  int DHWo = Do * Ho * Wo;
  int total = 2 * DHWo;
  int i = blockIdx.x * BLK + threadIdx.x;
  if (i >= total) return;
  int b = i / DHWo, sp = i - b * DHWo;
  int z = sp / (Ho * Wo); int r = sp - z * Ho * Wo; int y = r / Wo; int x = r - y * Wo;
  int Hi = 2 * Ho, Wi = 2 * Wo;
  const int* mb = mapp + b * 8 * DHWo;
  bool occ = false;
  for (int dz = 0; dz < 2; dz++)
    for (int dy = 0; dy < 2; dy++)
      for (int dx = 0; dx < 2; dx++)
        occ |= mb[((2 * z + dz) * Hi + 2 * y + dy) * Wi + 2 * x + dx] >= 0;
  if (occ) { int p = atomicAdd(cntc, 1); listc[p] = i; mapc[i] = p; }
  else mapc[i] = -1;
}

// Gather masked level-0 features (3ch) into compact channels-last rows.
__global__ void gather0_k(const float* __restrict__ feats, const int* __restrict__ list,
                          const int* __restrict__ cntp, float* __restrict__ rows, int DHW) {
  int n = *cntp;
  int t = blockIdx.x * BLK + threadIdx.x;
  if (t >= n * 3) return;
  int vox = t / 3, c = t - vox * 3;
  int idx = list[vox]; int b = idx / DHW, sp = idx - b * DHW;
  rows[t] = feats[(b * 3 + c) * DHW + sp];
}

// Weight transpose [O][I][K] -> [K][I][O] (conv1: K=1 -> [I][O]).
__global__ void wtr_k(const float* __restrict__ w, float* __restrict__ wt,
                      int O, int I, int K) {
  int t = blockIdx.x * BLK + threadIdx.x;
  int tot = O * I * K;
  if (t >= tot) return;
  int k = t % K; int rr = t / K; int ci = rr % I; int co = rr / I;
  wt[(k * I + ci) * O + co] = w[t];
}

// ---------------------------------------------------------------------------
// Sparse convs on compact channels-last rows. thread = (voxel, cout).
// Input row loads are wave-broadcast float4; weight loads coalesced in co.
// Empty taps (map<0) are skipped entirely.
// ---------------------------------------------------------------------------
template <int CIN, int COUT>
__global__ __launch_bounds__(BLK) void conv3_g(const float* __restrict__ fin,
    const float* __restrict__ wt, float* __restrict__ fout,
    const int* __restrict__ list, const int* __restrict__ map,
    const int* __restrict__ cntp, int D, int H, int W) {
  int n = *cntp;
  int t = blockIdx.x * BLK + threadIdx.x;
  if (t >= n * COUT) return;
  int vox = t / COUT, co = t - vox * COUT;
  int DHW = D * H * W;
  int idx = list[vox];
  int b = idx / DHW, sp = idx - b * DHW;
  int z = sp / (H * W); int r = sp - z * H * W; int y = r / W; int x = r - y * W;
  const int* mb = map + b * DHW;
  float acc = 0.f;
  for (int dz = -1; dz <= 1; dz++) {
    int zz = z + dz; if ((unsigned)zz >= (unsigned)D) continue;
    for (int dy = -1; dy <= 1; dy++) {
      int yy = y + dy; if ((unsigned)yy >= (unsigned)H) continue;
      for (int dx = -1; dx <= 1; dx++) {
        int xx = x + dx; if ((unsigned)xx >= (unsigned)W) continue;
        int j = mb[(zz * H + yy) * W + xx];
        if (j < 0) continue;
        int k = ((dz + 1) * 3 + (dy + 1)) * 3 + (dx + 1);
        const float* row = fin + (long)j * CIN;
        const float* wk = wt + (long)k * CIN * COUT + co;
        if constexpr (CIN % 4 == 0) {
          #pragma unroll 4
          for (int ci = 0; ci < CIN; ci += 4) {
            float4 rv = *reinterpret_cast<const float4*>(row + ci);
            acc += rv.x * wk[ci * COUT] + rv.y * wk[(ci + 1) * COUT]
                 + rv.z * wk[(ci + 2) * COUT] + rv.w * wk[(ci + 3) * COUT];
          }
        } else {
          for (int ci = 0; ci < CIN; ci++) acc += row[ci] * wk[ci * COUT];
        }
      }
    }
  }
  fout[(long)vox * COUT + co] = acc;
}

template <int CIN, int COUT>
__global__ __launch_bounds__(BLK) void conv2_g(const float* __restrict__ fin,
    const float* __restrict__ wt, float* __restrict__ fout,
    const int* __restrict__ list, const int* __restrict__ mapp,
    const int* __restrict__ cntp, int Do, int Ho, int Wo) {
  int n = *cntp;
  int t = blockIdx.x * BLK + threadIdx.x;
  if (t >= n * COUT) return;
  int vox = t / COUT, co = t - vox * COUT;
  int DHWo = Do * Ho * Wo, DHWi = 8 * DHWo;
  int Hi = 2 * Ho, Wi = 2 * Wo;
  int idx = list[vox];
  int b = idx / DHWo, sp = idx - b * DHWo;
  int z = sp / (Ho * Wo); int r = sp - z * Ho * Wo; int y = r / Wo; int x = r - y * Wo;
  const int* mb = mapp + b * DHWi;
  float acc = 0.f;
  #pragma unroll
  for (int k = 0; k < 8; k++) {
    int dz = k >> 2, dy = (k >> 1) & 1, dx = k & 1;
    int j = mb[((2 * z + dz) * Hi + 2 * y + dy) * Wi + 2 * x + dx];
    if (j < 0) continue;
    const float* row = fin + (long)j * CIN;
    const float* wk = wt + (long)k * CIN * COUT + co;
    #pragma unroll 4
    for (int ci = 0; ci < CIN; ci += 4) {
      float4 rv = *reinterpret_cast<const float4*>(row + ci);
      acc += rv.x * wk[ci * COUT] + rv.y * wk[(ci + 1) * COUT]
           + rv.z * wk[(ci + 2) * COUT] + rv.w * wk[(ci + 3) * COUT];
    }
  }
  fout[(long)vox * COUT + co] = acc;
}

template <int CIN, int COUT>
__global__ __launch_bounds__(BLK) void conv1_g(const float* __restrict__ fin,
    const float* __restrict__ wt, float* __restrict__ fout,
    const int* __restrict__ cntp) {
  int n = *cntp;
  int t = blockIdx.x * BLK + threadIdx.x;
  if (t >= n * COUT) return;
  int vox = t / COUT, co = t - vox * COUT;
  const float* row = fin + (long)vox * CIN;
  const float* wk = wt + co;
  float acc = 0.f;
  #pragma unroll 4
  for (int ci = 0; ci < CIN; ci += 4) {
    float4 rv = *reinterpret_cast<const float4*>(row + ci);
    acc += rv.x * wk[ci * COUT] + rv.y * wk[(ci + 1) * COUT]
         + rv.z * wk[(ci + 2) * COUT] + rv.w * wk[(ci + 3) * COUT];
  }
  fout[(long)vox * COUT + co] = acc;
}

// ---------------------------------------------------------------------------
// BN stats over compact rows: slot[c]=sum, slot[256+c]=sumsq (atomic per block).
// ---------------------------------------------------------------------------
template <int C>
__global__ __launch_bounds__(BLK) void bnred_k(const float* __restrict__ rows,
    const int* __restrict__ cntp, float* __restrict__ slot) {
  int n = *cntp;
  int tot = n * C;
  int tid = threadIdx.x;
  float s = 0.f, s2 = 0.f;
  for (int t = blockIdx.x * BLK + tid; t < tot; t += gridDim.x * BLK) {
    float v = rows[t]; s += v; s2 += v * v;
  }
  __shared__ float sh[BLK], sh2[BLK];
  sh[tid] = s; sh2[tid] = s2;
  __syncthreads();
  for (int o = BLK / 2; o >= C; o >>= 1) {
    if (tid < o) { sh[tid] += sh[tid + o]; sh2[tid] += sh2[tid + o]; }
    __syncthreads();
  }
  if (tid < C) { atomicAdd(&slot[tid], sh[tid]); atomicAdd(&slot[256 + tid], sh2[tid]); }
}

// Fused BN scale/shift (computed inline from sums) + skip + ReLU.
// mode 0: relu(bn(x)); 1: relu(bn(x)+bn2(aux)); 2: relu(bn(x)+aux)
__global__ void bnapp_k(const float* __restrict__ xin, const float* __restrict__ aux,
                        const float* __restrict__ slot, const float* __restrict__ slot2,
                        const int* __restrict__ cntp, float* __restrict__ out,
                        int Cmask, int mode) {
  int n = *cntp;
  int tot = n * (Cmask + 1);
  int t = blockIdx.x * BLK + threadIdx.x;
  if (t >= tot) return;
  int c = t & Cmask;
  float cnt = fmaxf((float)n, 1.f);
  float mean = slot[c] / cnt;
  float var = fmaxf(slot[256 + c] / cnt - mean * mean, 0.f);
  float a = rsqrtf(var + 1e-5f);
  float v = xin[t] * a - mean * a;
  if (mode == 1) {
    float mean2 = slot2[c] / cnt;
    float var2 = fmaxf(slot2[256 + c] / cnt - mean2 * mean2, 0.f);
    float a2 = rsqrtf(var2 + 1e-5f);
    v += aux[t] * a2 - mean2 * a2;
  } else if (mode == 2) v += aux[t];
  out[t] = fmaxf(v, 0.f);
}

// Final scatter of compact rows to dense output (d_out pre-zeroed).
__global__ void scatter_k(const float* __restrict__ rows, const int* __restrict__ list,
                          const int* __restrict__ cntp, float* __restrict__ out, int DHW) {
  int n = *cntp;
  int t = blockIdx.x * BLK + threadIdx.x;
  if (t >= n * 256) return;
  int vox = t >> 8, c = t & 255;
  int idx = list[vox]; int b = idx / DHW, sp = idx - b * DHW;
  out[(b * 256 + c) * DHW + sp] = rows[t];
}

// ---------------------------------------------------------------------------
// Host side
// ---------------------------------------------------------------------------
static inline int gup(long work) { return (int)((work + BLK - 1) / BLK); }

template <int Cp, int Co>
static void stage_h(const float* pin, const float* wdT, const float* wa1T, const float* wb1T,
                    const float* wskT, const float* wa2T, const float* wb2T,
                    const int* mapp, int* mapc, int* listc, int* cntc,
                    int Do, int Ho, int Wo, int capc,
                    float* R0, float* R1, float* R2, float* R3,
                    float* stats, int& slot, hipStream_t s) {
  int tot = 2 * Do * Ho * Wo;
  downmap_k<<<gup(tot), BLK, 0, s>>>(mapp, mapc, listc, cntc, Do, Ho, Wo);
  int gP = gup((long)capc * Cp), gO = gup((long)capc * Co);
  int rP = gP < 1024 ? gP : 1024, rO = gO < 1024 ? gO : 1024;

  conv2_g<Cp, Cp><<<gP, BLK, 0, s>>>(pin, wdT, R0, listc, mapp, cntc, Do, Ho, Wo);
  float* sl = stats + (slot++) * 1024;
  bnred_k<Cp><<<rP, BLK, 0, s>>>(R0, cntc, sl);
  bnapp_k<<<gP, BLK, 0, s>>>(R0, nullptr, sl, nullptr, cntc, R0, Cp - 1, 0);

  conv3_g<Cp, Co><<<gO, BLK, 0, s>>>(R0, wa1T, R1, listc, mapc, cntc, Do, Ho, Wo);
  sl = stats + (slot++) * 1024;
  bnred_k<Co><<<rO, BLK, 0, s>>>(R1, cntc, sl);
  bnapp_k<<<gO, BLK, 0, s>>>(R1, nullptr, sl, nullptr, cntc, R1, Co - 1, 0);

  conv3_g<Co, Co><<<gO, BLK, 0, s>>>(R1, wb1T, R2, listc, mapc, cntc, Do, Ho, Wo);
  float* slB = stats + (slot++) * 1024;
  bnred_k<Co><<<rO, BLK, 0, s>>>(R2, cntc, slB);
  if (wskT) {
    conv1_g<Cp, Co><<<gO, BLK, 0, s>>>(R0, wskT, R3, cntc);
    float* slS = stats + (slot++) * 1024;
    bnred_k<Co><<<rO, BLK, 0, s>>>(R3, cntc, slS);
    bnapp_k<<<gO, BLK, 0, s>>>(R2, R3, slB, slS, cntc, R2, Co - 1, 1);
  } else {
    bnapp_k<<<gO, BLK, 0, s>>>(R2, R0, slB, nullptr, cntc, R2, Co - 1, 2);
  }

  conv3_g<Co, Co><<<gO, BLK, 0, s>>>(R2, wa2T, R1, listc, mapc, cntc, Do, Ho, Wo);
  sl = stats + (slot++) * 1024;
  bnred_k<Co><<<rO, BLK, 0, s>>>(R1, cntc, sl);
  bnapp_k<<<gO, BLK, 0, s>>>(R1, nullptr, sl, nullptr, cntc, R1, Co - 1, 0);

  conv3_g<Co, Co><<<gO, BLK, 0, s>>>(R1, wb2T, R3, listc, mapc, cntc, Do, Ho, Wo);
  slB = stats + (slot++) * 1024;
  bnred_k<Co><<<rO, BLK, 0, s>>>(R3, cntc, slB);
  bnapp_k<<<gO, BLK, 0, s>>>(R3, R2, slB, nullptr, cntc, R3, Co - 1, 2);
}

// weight transpose table: input idx, O, I, K
static const int WT_TAB[25][4] = {
  {2, 32, 3, 27},  {3, 32, 32, 27}, {4, 32, 32, 8},  {5, 32, 32, 27}, {6, 32, 32, 27},
  {7, 32, 32, 27}, {8, 32, 32, 27}, {9, 32, 32, 8},  {10, 64, 32, 27},{11, 64, 64, 27},
  {12, 64, 32, 1}, {13, 64, 64, 27},{14, 64, 64, 27},{15, 64, 64, 8}, {16, 128, 64, 27},
  {17, 128, 128, 27},{18, 128, 64, 1},{19, 128, 128, 27},{20, 128, 128, 27},
  {21, 128, 128, 8},{22, 256, 128, 27},{23, 256, 128, 1},{24, 256, 128, 1},{25, 256, 256, 27},
  {26, 256, 256, 27},
};
// NOTE: rows for 23 (b41) and 24 (k4) fixed below in code (table kept simple).

#define CAP0 80000
#define CAP1 65536
#define CAP2 8192
#define CAP3 1024
#define CAP4 128

extern "C" void kernel_launch(void* const* d_in, const int* in_sizes, int n_in,
                              void* d_out, int out_size, void* d_ws, size_t ws_size,
                              hipStream_t stream) {
  const float* feats = (const float*)d_in[0];
  const float* mask0 = (const float*)d_in[1];

  char* p = (char*)d_ws;
  auto alloc = [&](size_t bytes) { char* r = p; p += (bytes + 255) & ~255ull; return r; };

  // transposed weights
  float* wT[27] = {nullptr};
  int O_[27], I_[27], K_[27];
  {
    // full explicit shape table (idx: O, I, K)
    const int tab[25][4] = {
      {2, 32, 3, 27},  {3, 32, 32, 27}, {4, 32, 32, 8},  {5, 32, 32, 27}, {6, 32, 32, 27},
      {7, 32, 32, 27}, {8, 32, 32, 27}, {9, 32, 32, 8},  {10, 64, 32, 27},{11, 64, 64, 27},
      {12, 64, 32, 1}, {13, 64, 64, 27},{14, 64, 64, 27},{15, 64, 64, 8}, {16, 128, 64, 27},
      {17, 128, 128, 27},{18, 128, 64, 1},{19, 128, 128, 27},{20, 128, 128, 27},
      {21, 128, 128, 8},{22, 256, 128, 27},{23, 256, 256, 27},{24, 256, 128, 1},
      {25, 256, 256, 27},{26, 256, 256, 27},
    };
    for (int i = 0; i < 25; i++) {
      int idx = tab[i][0], O = tab[i][1], I = tab[i][2], K = tab[i][3];
      O_[idx] = O; I_[idx] = I; K_[idx] = K;
      wT[idx] = (float*)alloc((size_t)O * I * K * 4);
    }
  }

  int* map0 = (int*)alloc(524288 * 4);
  int* list0 = (int*)alloc(524288 * 4);
  int* map1 = (int*)alloc(65536 * 4);
  int* list1 = (int*)alloc(65536 * 4);
  int* map2 = (int*)alloc(8192 * 4);
  int* list2 = (int*)alloc(8192 * 4);
  int* map3 = (int*)alloc(1024 * 4);
  int* list3 = (int*)alloc(1024 * 4);
  int* map4 = (int*)alloc(128 * 4);
  int* list4 = (int*)alloc(128 * 4);
  int* cnts = (int*)alloc(32 * 4);
  float* stats = (float*)alloc(32 * 1024 * 4);
  float* G0 = (float*)alloc((size_t)CAP0 * 3 * 4);
  float* F0a = (float*)alloc((size_t)CAP0 * 32 * 4);
  float* F0b = (float*)alloc((size_t)CAP0 * 32 * 4);
  float* L1R[4], *L2R[4], *L3R[4], *L4R[4];
  for (int i = 0; i < 4; i++) L1R[i] = (float*)alloc((size_t)CAP1 * 32 * 4);
  for (int i = 0; i < 4; i++) L2R[i] = (float*)alloc((size_t)CAP2 * 64 * 4);
  for (int i = 0; i < 4; i++) L3R[i] = (float*)alloc((size_t)CAP3 * 128 * 4);
  for (int i = 0; i < 4; i++) L4R[i] = (float*)alloc((size_t)CAP4 * 256 * 4);

  // per-call zeroing (ws/d_out are not re-poisoned between replays)
  hipMemsetAsync(cnts, 0, 32 * 4, stream);
  hipMemsetAsync(stats, 0, 32 * 1024 * 4, stream);
  hipMemsetAsync(d_out, 0, (size_t)out_size * 4, stream);

  // weight transposes
  for (int idx = 2; idx <= 26; idx++) {
    long tot = (long)O_[idx] * I_[idx] * K_[idx];
    wtr_k<<<gup(tot), BLK, 0, stream>>>((const float*)d_in[idx], wT[idx],
                                        O_[idx], I_[idx], K_[idx]);
  }

  int slot = 0;
  // level 0: map + gather
  build_map0_k<<<gup(524288), BLK, 0, stream>>>(mask0, map0, list0, cnts + 0, 524288, CAP0);
  gather0_k<<<gup((long)CAP0 * 3), BLK, 0, stream>>>(feats, list0, cnts + 0, G0, 262144);

  int g0 = gup((long)CAP0 * 32);
  int r0 = g0 < 1024 ? g0 : 1024;
  conv3_g<3, 32><<<g0, BLK, 0, stream>>>(G0, wT[2], F0a, list0, map0, cnts + 0, 64, 64, 64);
  float* sl = stats + (slot++) * 1024;
  bnred_k<32><<<r0, BLK, 0, stream>>>(F0a, cnts + 0, sl);
  bnapp_k<<<g0, BLK, 0, stream>>>(F0a, nullptr, sl, nullptr, cnts + 0, F0a, 31, 0);

  conv3_g<32, 32><<<g0, BLK, 0, stream>>>(F0a, wT[3], F0b, list0, map0, cnts + 0, 64, 64, 64);
  sl = stats + (slot++) * 1024;
  bnred_k<32><<<r0, BLK, 0, stream>>>(F0b, cnts + 0, sl);
  bnapp_k<<<g0, BLK, 0, stream>>>(F0b, nullptr, sl, nullptr, cnts + 0, F0b, 31, 0);

  stage_h<32, 32>(F0b, wT[4], wT[5], wT[6], nullptr, wT[7], wT[8],
                  map0, map1, list1, cnts + 1, 32, 32, 32, CAP1,
                  L1R[0], L1R[1], L1R[2], L1R[3], stats, slot, stream);
  stage_h<32, 64>(L1R[3], wT[9], wT[10], wT[11], wT[12], wT[13], wT[14],
                  map1, map2, list2, cnts + 2, 16, 16, 16, CAP2,
                  L2R[0], L2R[1], L2R[2], L2R[3], stats, slot, stream);
  stage_h<64, 128>(L2R[3], wT[15], wT[16], wT[17], wT[18], wT[19], wT[20],
                   map2, map3, list3, cnts + 3, 8, 8, 8, CAP3,
                   L3R[0], L3R[1], L3R[2], L3R[3], stats, slot, stream);
  stage_h<128, 256>(L3R[3], wT[21], wT[22], wT[23], wT[24], wT[25], wT[26],
                    map3, map4, list4, cnts + 4, 4, 4, 4, CAP4,
                    L4R[0], L4R[1], L4R[2], L4R[3], stats, slot, stream);

  scatter_k<<<gup((long)CAP4 * 256), BLK, 0, stream>>>(L4R[3], list4, cnts + 4,
                                                      (float*)d_out, 64);
}

// Round 3
// 2065.089 us; speedup vs baseline: 15.2473x; 1.5799x over previous
//
#include <hip/hip_runtime.h>

#define BLK 256

static inline int gup(long work) { return (int)((work + BLK - 1) / BLK); }
static inline int gup1024(long work) { return (int)((work + 1023) / 1024); }

// ---------------------------------------------------------------------------
// Ordered compaction: cnt_k (per-block counts) -> scan_k (exclusive) -> emit_k.
// mode 0: occupancy from float mask. mode 1: any of 8 children occupied in
// fine map (fmap), coarse dims Do,Ho,Wo with DHW = Do*Ho*Wo.
// ---------------------------------------------------------------------------
__device__ inline bool occ_pred(const float* mask, const int* fmap,
                                int i, int DHW, int Ho, int Wo, int mode) {
  if (mode == 0) return mask[i] > 0.f;
  int b = i / DHW, sp = i - b * DHW;
  int HW = Ho * Wo;
  int z = sp / HW, r = sp - z * HW, y = r / Wo, x = r - y * Wo;
  int Hi = 2 * Ho, Wi = 2 * Wo;
  const int* mb = fmap + b * 8 * DHW;
  int base = ((2 * z) * Hi + 2 * y) * Wi + 2 * x;
  bool occ = false;
  for (int dz = 0; dz < 2; dz++)
    for (int dy = 0; dy < 2; dy++)
      for (int dx = 0; dx < 2; dx++)
        occ |= mb[base + dz * Hi * Wi + dy * Wi + dx] >= 0;
  return occ;
}

__global__ __launch_bounds__(1024) void cnt_k(const float* mask, const int* fmap,
    int* bcnt, int DHW, int Ho, int Wo, int mode, int total) {
  int i = blockIdx.x * 1024 + threadIdx.x;
  bool occ = (i < total) && occ_pred(mask, fmap, i, DHW, Ho, Wo, mode);
  unsigned long long bal = __ballot(occ);
  __shared__ int ws[16];
  int lane = threadIdx.x & 63, wid = threadIdx.x >> 6;
  if (lane == 0) ws[wid] = __popcll(bal);
  __syncthreads();
  if (threadIdx.x == 0) {
    int a = 0;
    for (int w = 0; w < 16; w++) a += ws[w];
    bcnt[blockIdx.x] = a;
  }
}

__global__ __launch_bounds__(1024) void scan_k(int* bcnt, int nb, int* cnt) {
  __shared__ int sh[1024];
  int t = threadIdx.x;
  int v = (t < nb) ? bcnt[t] : 0;
  sh[t] = v;
  __syncthreads();
  for (int o = 1; o < 1024; o <<= 1) {
    int u = (t >= o) ? sh[t - o] : 0;
    __syncthreads();
    sh[t] += u;
    __syncthreads();
  }
  if (t < nb) bcnt[t] = sh[t] - v;  // exclusive
  if (t == 0) *cnt = sh[1023];
}

__global__ __launch_bounds__(1024) void emit_k(const float* mask, const int* fmap,
    const int* boff, int* map, int* list, int DHW, int Ho, int Wo, int mode, int total) {
  int i = blockIdx.x * 1024 + threadIdx.x;
  bool occ = (i < total) && occ_pred(mask, fmap, i, DHW, Ho, Wo, mode);
  unsigned long long bal = __ballot(occ);
  int lane = threadIdx.x & 63, wid = threadIdx.x >> 6;
  __shared__ int wcnt[16], woff[16];
  if (lane == 0) wcnt[wid] = __popcll(bal);
  __syncthreads();
  if (threadIdx.x == 0) {
    int a = boff[blockIdx.x];
    for (int w = 0; w < 16; w++) { woff[w] = a; a += wcnt[w]; }
  }
  __syncthreads();
  if (i < total) {
    if (occ) {
      int p = woff[wid] + __popcll(bal & ((1ull << lane) - 1ull));
      map[i] = p; list[p] = i;
    } else map[i] = -1;
  }
}

// Gather level-0 feats (3ch) into compact rows padded to 4ch.
__global__ void gather0_k(const float* __restrict__ feats, const int* __restrict__ list,
                          const int* __restrict__ cntp, float* __restrict__ rows, int DHW) {
  int n = *cntp;
  int t = blockIdx.x * BLK + threadIdx.x;
  if (t >= n * 4) return;
  int vox = t >> 2, c = t & 3;
  int idx = list[vox]; int b = idx / DHW, sp = idx - b * DHW;
  rows[t] = (c < 3) ? feats[(b * 3 + c) * DHW + sp] : 0.f;
}

// Weight transform [O][I][K] -> [k][ci4][co][4] (zero-padded in ci).
__global__ void wtr4_k(const float* __restrict__ w, float* __restrict__ wt,
                       int O, int I, int K, int I4) {
  int t = blockIdx.x * BLK + threadIdx.x;
  int tot = K * I4 * O * 4;
  if (t >= tot) return;
  int e = t & 3; int r = t >> 2;
  int co = r % O; int r2 = r / O; int ci4 = r2 % I4; int k = r2 / I4;
  int ci = 4 * ci4 + e;
  wt[t] = (ci < I) ? w[(co * I + ci) * K + k] : 0.f;
}

// ---------------------------------------------------------------------------
// Register-tiled sparse convs. Block: 256 threads = CL co-lanes x G groups.
// Each thread: VX voxels x 2 couts. js double-buffered in LDS to hide map
// lookup latency. TG = tap-group split (blockIdx.y), atomicAdd epilogue.
// ---------------------------------------------------------------------------
template <int CIN, int COUT, int VX, int TG>
__global__ __launch_bounds__(256) void conv3_t(
    const float* __restrict__ fin, const float* __restrict__ wt,
    float* __restrict__ fout, const int* __restrict__ list,
    const int* __restrict__ map, const int* __restrict__ cntp,
    const float* __restrict__ zrow, int D, int H, int W) {
  constexpr int CL = COUT / 2, G = 256 / CL, VT = G * VX;
  int n = *cntp;
  int vb = blockIdx.x * VT;
  if (vb >= n) return;
  int DHW = D * H * W;
  __shared__ int js[2][VT];
  __shared__ int sz[VT], sy[VT], sx2[VT], sb[VT];
  int tid = threadIdx.x;
  if (tid < VT) {
    int v = vb + tid;
    if (v < n) {
      int idx = list[v];
      int b = idx / DHW, sp = idx - b * DHW;
      int z = sp / (H * W), r = sp - z * H * W, y = r / W, x = r - y * W;
      sz[tid] = z; sy[tid] = y; sx2[tid] = x; sb[tid] = b * DHW;
    } else sb[tid] = -1;
  }
  __syncthreads();
  const int tg = (TG > 1) ? blockIdx.y : 0;
  const int nt = (27 - tg + TG - 1) / TG;
  auto lookup = [&](int i) -> int {
    int k = tg + i * TG;
    if (sb[tid] < 0) return -1;
    int dz = k / 9, dy = (k / 3) % 3, dx = k % 3;
    int zz = sz[tid] + dz - 1, yy = sy[tid] + dy - 1, xx = sx2[tid] + dx - 1;
    if ((unsigned)zz >= (unsigned)D || (unsigned)yy >= (unsigned)H ||
        (unsigned)xx >= (unsigned)W) return -1;
    return map[sb[tid] + (zz * H + yy) * W + xx];
  };
  if (tid < VT) js[0][tid] = lookup(0);
  __syncthreads();
  int cl = tid % CL, g = tid / CL, vg = g * VX;
  float acc[VX][2];
  #pragma unroll
  for (int v = 0; v < VX; v++) { acc[v][0] = 0.f; acc[v][1] = 0.f; }
  for (int i = 0; i < nt; i++) {
    int cur = i & 1;
    if (tid < VT && i + 1 < nt) js[cur ^ 1][tid] = lookup(i + 1);
    const float* rows[VX];
    bool any = false;
    #pragma unroll
    for (int v = 0; v < VX; v++) {
      int j = js[cur][vg + v];
      rows[v] = (j >= 0) ? fin + (long)j * CIN : zrow;
      any |= (j >= 0);
    }
    if (any) {
      int k = tg + i * TG;
      const float4* wk = (const float4*)wt + ((long)k * (CIN / 4)) * COUT + cl;
      #pragma unroll 4
      for (int c4 = 0; c4 < CIN / 4; c4++) {
        float4 w0 = wk[c4 * COUT];
        float4 w1 = wk[c4 * COUT + CL];
        #pragma unroll
        for (int v = 0; v < VX; v++) {
          float4 rv = *(const float4*)(rows[v] + 4 * c4);
          acc[v][0] += rv.x * w0.x + rv.y * w0.y + rv.z * w0.z + rv.w * w0.w;
          acc[v][1] += rv.x * w1.x + rv.y * w1.y + rv.z * w1.z + rv.w * w1.w;
        }
      }
    }
    __syncthreads();
  }
  #pragma unroll
  for (int v = 0; v < VX; v++) {
    int vo = vb + vg + v;
    if (vo < n) {
      if constexpr (TG > 1) {
        atomicAdd(&fout[(long)vo * COUT + cl], acc[v][0]);
        atomicAdd(&fout[(long)vo * COUT + cl + CL], acc[v][1]);
      } else {
        fout[(long)vo * COUT + cl] = acc[v][0];
        fout[(long)vo * COUT + cl + CL] = acc[v][1];
      }
    }
  }
}

template <int CIN, int COUT, int VX, int TG>
__global__ __launch_bounds__(256) void conv2_t(
    const float* __restrict__ fin, const float* __restrict__ wt,
    float* __restrict__ fout, const int* __restrict__ list,
    const int* __restrict__ fmap, const int* __restrict__ cntp,
    const float* __restrict__ zrow, int Do, int Ho, int Wo) {
  constexpr int CL = COUT / 2, G = 256 / CL, VT = G * VX;
  int n = *cntp;
  int vb = blockIdx.x * VT;
  if (vb >= n) return;
  int DHWc = Do * Ho * Wo;
  int Hi = 2 * Ho, Wi = 2 * Wo;
  __shared__ int js[2][VT];
  __shared__ int sz[VT], sy[VT], sx2[VT], sb[VT];
  int tid = threadIdx.x;
  if (tid < VT) {
    int v = vb + tid;
    if (v < n) {
      int idx = list[v];
      int b = idx / DHWc, sp = idx - b * DHWc;
      int z = sp / (Ho * Wo), r = sp - z * Ho * Wo, y = r / Wo, x = r - y * Wo;
      sz[tid] = 2 * z; sy[tid] = 2 * y; sx2[tid] = 2 * x; sb[tid] = b * 8 * DHWc;
    } else sb[tid] = -1;
  }
  __syncthreads();
  const int tg = (TG > 1) ? blockIdx.y : 0;
  const int nt = (8 - tg + TG - 1) / TG;
  auto lookup = [&](int i) -> int {
    int k = tg + i * TG;
    if (sb[tid] < 0) return -1;
    int dz = k >> 2, dy = (k >> 1) & 1, dx = k & 1;
    return fmap[sb[tid] + ((sz[tid] + dz) * Hi + sy[tid] + dy) * Wi + sx2[tid] + dx];
  };
  if (tid < VT) js[0][tid] = lookup(0);
  __syncthreads();
  int cl = tid % CL, g = tid / CL, vg = g * VX;
  float acc[VX][2];
  #pragma unroll
  for (int v = 0; v < VX; v++) { acc[v][0] = 0.f; acc[v][1] = 0.f; }
  for (int i = 0; i < nt; i++) {
    int cur = i & 1;
    if (tid < VT && i + 1 < nt) js[cur ^ 1][tid] = lookup(i + 1);
    const float* rows[VX];
    bool any = false;
    #pragma unroll
    for (int v = 0; v < VX; v++) {
      int j = js[cur][vg + v];
      rows[v] = (j >= 0) ? fin + (long)j * CIN : zrow;
      any |= (j >= 0);
    }
    if (any) {
      int k = tg + i * TG;
      const float4* wk = (const float4*)wt + ((long)k * (CIN / 4)) * COUT + cl;
      #pragma unroll 4
      for (int c4 = 0; c4 < CIN / 4; c4++) {
        float4 w0 = wk[c4 * COUT];
        float4 w1 = wk[c4 * COUT + CL];
        #pragma unroll
        for (int v = 0; v < VX; v++) {
          float4 rv = *(const float4*)(rows[v] + 4 * c4);
          acc[v][0] += rv.x * w0.x + rv.y * w0.y + rv.z * w0.z + rv.w * w0.w;
          acc[v][1] += rv.x * w1.x + rv.y * w1.y + rv.z * w1.z + rv.w * w1.w;
        }
      }
    }
    __syncthreads();
  }
  #pragma unroll
  for (int v = 0; v < VX; v++) {
    int vo = vb + vg + v;
    if (vo < n) {
      if constexpr (TG > 1) {
        atomicAdd(&fout[(long)vo * COUT + cl], acc[v][0]);
        atomicAdd(&fout[(long)vo * COUT + cl + CL], acc[v][1]);
      } else {
        fout[(long)vo * COUT + cl] = acc[v][0];
        fout[(long)vo * COUT + cl + CL] = acc[v][1];
      }
    }
  }
}

template <int CIN, int COUT, int VX>
__global__ __launch_bounds__(256) void conv1_t(
    const float* __restrict__ fin, const float* __restrict__ wt,
    float* __restrict__ fout, const int* __restrict__ cntp,
    const float* __restrict__ zrow) {
  constexpr int CL = COUT / 2, G = 256 / CL, VT = G * VX;
  int n = *cntp;
  int vb = blockIdx.x * VT;
  if (vb >= n) return;
  int tid = threadIdx.x;
  int cl = tid % CL, g = tid / CL, vg = g * VX;
  const float* rows[VX];
  #pragma unroll
  for (int v = 0; v < VX; v++) {
    int vo = vb + vg + v;
    rows[v] = (vo < n) ? fin + (long)vo * CIN : zrow;
  }
  float acc[VX][2];
  #pragma unroll
  for (int v = 0; v < VX; v++) { acc[v][0] = 0.f; acc[v][1] = 0.f; }
  const float4* wk = (const float4*)wt + cl;
  #pragma unroll 4
  for (int c4 = 0; c4 < CIN / 4; c4++) {
    float4 w0 = wk[c4 * COUT];
    float4 w1 = wk[c4 * COUT + CL];
    #pragma unroll
    for (int v = 0; v < VX; v++) {
      float4 rv = *(const float4*)(rows[v] + 4 * c4);
      acc[v][0] += rv.x * w0.x + rv.y * w0.y + rv.z * w0.z + rv.w * w0.w;
      acc[v][1] += rv.x * w1.x + rv.y * w1.y + rv.z * w1.z + rv.w * w1.w;
    }
  }
  #pragma unroll
  for (int v = 0; v < VX; v++) {
    int vo = vb + vg + v;
    if (vo < n) {
      fout[(long)vo * COUT + cl] = acc[v][0];
      fout[(long)vo * COUT + cl + CL] = acc[v][1];
    }
  }
}

// ---------------------------------------------------------------------------
// BN stats + fused apply (unchanged structure from round 2).
// ---------------------------------------------------------------------------
template <int C>
__global__ __launch_bounds__(BLK) void bnred_k(const float* __restrict__ rows,
    const int* __restrict__ cntp, float* __restrict__ slot) {
  int n = *cntp;
  int tot = n * C;
  int tid = threadIdx.x;
  float s = 0.f, s2 = 0.f;
  for (int t = blockIdx.x * BLK + tid; t < tot; t += gridDim.x * BLK) {
    float v = rows[t]; s += v; s2 += v * v;
  }
  __shared__ float sh[BLK], sh2[BLK];
  sh[tid] = s; sh2[tid] = s2;
  __syncthreads();
  for (int o = BLK / 2; o >= C; o >>= 1) {
    if (tid < o) { sh[tid] += sh[tid + o]; sh2[tid] += sh2[tid + o]; }
    __syncthreads();
  }
  if (tid < C) { atomicAdd(&slot[tid], sh[tid]); atomicAdd(&slot[256 + tid], sh2[tid]); }
}

__global__ void bnapp_k(const float* __restrict__ xin, const float* __restrict__ aux,
                        const float* __restrict__ slot, const float* __restrict__ slot2,
                        const int* __restrict__ cntp, float* __restrict__ out,
                        int Cmask, int mode) {
  int n = *cntp;
  int tot = n * (Cmask + 1);
  int t = blockIdx.x * BLK + threadIdx.x;
  if (t >= tot) return;
  int c = t & Cmask;
  float cnt = fmaxf((float)n, 1.f);
  float mean = slot[c] / cnt;
  float var = fmaxf(slot[256 + c] / cnt - mean * mean, 0.f);
  float a = rsqrtf(var + 1e-5f);
  float v = xin[t] * a - mean * a;
  if (mode == 1) {
    float mean2 = slot2[c] / cnt;
    float var2 = fmaxf(slot2[256 + c] / cnt - mean2 * mean2, 0.f);
    float a2 = rsqrtf(var2 + 1e-5f);
    v += aux[t] * a2 - mean2 * a2;
  } else if (mode == 2) v += aux[t];
  out[t] = fmaxf(v, 0.f);
}

__global__ void scatter_k(const float* __restrict__ rows, const int* __restrict__ list,
                          const int* __restrict__ cntp, float* __restrict__ out, int DHW) {
  int n = *cntp;
  int t = blockIdx.x * BLK + threadIdx.x;
  if (t >= n * 256) return;
  int vox = t >> 8, c = t & 255;
  int idx = list[vox]; int b = idx / DHW, sp = idx - b * DHW;
  out[(b * 256 + c) * DHW + sp] = rows[t];
}

// ---------------------------------------------------------------------------
// Host side
// ---------------------------------------------------------------------------
#define CAP0 98304
#define CAP1 65536
#define CAP2 8192
#define CAP3 1024
#define CAP4 128

template <int Cp, int Co, int TG2, int TG3>
static void stage_h(const float* pin, const float* wd, const float* wa1, const float* wb1,
                    const float* wsk, const float* wa2, const float* wb2,
                    const int* mapp, int* mapc, int* listc, int* cntc, int* bcnt,
                    int Do, int Ho, int Wo, int capc,
                    float* R0, float* R1, float* R2, float* R3, const float* zrow,
                    float* stats, int& slot, hipStream_t s) {
  int DHWc = Do * Ho * Wo, total = 2 * DHWc;
  int nbl = gup1024(total);
  cnt_k<<<nbl, 1024, 0, s>>>(nullptr, mapp, bcnt, DHWc, Ho, Wo, 1, total);
  scan_k<<<1, 1024, 0, s>>>(bcnt, nbl, cntc);
  emit_k<<<nbl, 1024, 0, s>>>(nullptr, mapp, bcnt, mapc, listc, DHWc, Ho, Wo, 1, total);

  constexpr int VTp = 4096 / Cp, VTo = 4096 / Co;
  int gP = (capc + VTp - 1) / VTp, gO = (capc + VTo - 1) / VTo;
  int rP = gup((long)capc * Cp); if (rP > 1024) rP = 1024;
  int rO = gup((long)capc * Co); if (rO > 1024) rO = 1024;
  int aP = gup((long)capc * Cp), aO = gup((long)capc * Co);

  if (TG2 > 1) hipMemsetAsync(R0, 0, (size_t)capc * Cp * 4, s);
  conv2_t<Cp, Cp, 8, TG2><<<dim3(gP, TG2), 256, 0, s>>>(pin, wd, R0, listc, mapp, cntc, zrow, Do, Ho, Wo);
  float* sl = stats + (slot++) * 1024;
  bnred_k<Cp><<<rP, BLK, 0, s>>>(R0, cntc, sl);
  bnapp_k<<<aP, BLK, 0, s>>>(R0, nullptr, sl, nullptr, cntc, R0, Cp - 1, 0);

  if (TG3 > 1) hipMemsetAsync(R1, 0, (size_t)capc * Co * 4, s);
  conv3_t<Cp, Co, 8, TG3><<<dim3(gO, TG3), 256, 0, s>>>(R0, wa1, R1, listc, mapc, cntc, zrow, Do, Ho, Wo);
  sl = stats + (slot++) * 1024;
  bnred_k<Co><<<rO, BLK, 0, s>>>(R1, cntc, sl);
  bnapp_k<<<aO, BLK, 0, s>>>(R1, nullptr, sl, nullptr, cntc, R1, Co - 1, 0);

  if (TG3 > 1) hipMemsetAsync(R2, 0, (size_t)capc * Co * 4, s);
  conv3_t<Co, Co, 8, TG3><<<dim3(gO, TG3), 256, 0, s>>>(R1, wb1, R2, listc, mapc, cntc, zrow, Do, Ho, Wo);
  float* slB = stats + (slot++) * 1024;
  bnred_k<Co><<<rO, BLK, 0, s>>>(R2, cntc, slB);
  if (wsk) {
    conv1_t<Cp, Co, 8><<<gO, 256, 0, s>>>(R0, wsk, R3, cntc, zrow);
    float* slS = stats + (slot++) * 1024;
    bnred_k<Co><<<rO, BLK, 0, s>>>(R3, cntc, slS);
    bnapp_k<<<aO, BLK, 0, s>>>(R2, R3, slB, slS, cntc, R2, Co - 1, 1);
  } else {
    bnapp_k<<<aO, BLK, 0, s>>>(R2, R0, slB, nullptr, cntc, R2, Co - 1, 2);
  }

  if (TG3 > 1) hipMemsetAsync(R1, 0, (size_t)capc * Co * 4, s);
  conv3_t<Co, Co, 8, TG3><<<dim3(gO, TG3), 256, 0, s>>>(R2, wa2, R1, listc, mapc, cntc, zrow, Do, Ho, Wo);
  sl = stats + (slot++) * 1024;
  bnred_k<Co><<<rO, BLK, 0, s>>>(R1, cntc, sl);
  bnapp_k<<<aO, BLK, 0, s>>>(R1, nullptr, sl, nullptr, cntc, R1, Co - 1, 0);

  if (TG3 > 1) hipMemsetAsync(R3, 0, (size_t)capc * Co * 4, s);
  conv3_t<Co, Co, 8, TG3><<<dim3(gO, TG3), 256, 0, s>>>(R1, wb2, R3, listc, mapc, cntc, zrow, Do, Ho, Wo);
  slB = stats + (slot++) * 1024;
  bnred_k<Co><<<rO, BLK, 0, s>>>(R3, cntc, slB);
  bnapp_k<<<aO, BLK, 0, s>>>(R3, R2, slB, nullptr, cntc, R3, Co - 1, 2);
}

extern "C" void kernel_launch(void* const* d_in, const int* in_sizes, int n_in,
                              void* d_out, int out_size, void* d_ws, size_t ws_size,
                              hipStream_t stream) {
  const float* feats = (const float*)d_in[0];
  const float* mask0 = (const float*)d_in[1];

  char* p = (char*)d_ws;
  auto alloc = [&](size_t bytes) { char* r = p; p += (bytes + 255) & ~255ull; return r; };

  // weight shape table (idx: O, I, K)
  const int tab[25][4] = {
    {2, 32, 3, 27},  {3, 32, 32, 27}, {4, 32, 32, 8},  {5, 32, 32, 27}, {6, 32, 32, 27},
    {7, 32, 32, 27}, {8, 32, 32, 27}, {9, 32, 32, 8},  {10, 64, 32, 27},{11, 64, 64, 27},
    {12, 64, 32, 1}, {13, 64, 64, 27},{14, 64, 64, 27},{15, 64, 64, 8}, {16, 128, 64, 27},
    {17, 128, 128, 27},{18, 128, 64, 1},{19, 128, 128, 27},{20, 128, 128, 27},
    {21, 128, 128, 8},{22, 256, 128, 27},{23, 256, 256, 27},{24, 256, 128, 1},
    {25, 256, 256, 27},{26, 256, 256, 27},
  };
  float* wT[27] = {nullptr};
  int O_[27], I_[27], K_[27], I4_[27];
  for (int i = 0; i < 25; i++) {
    int idx = tab[i][0], O = tab[i][1], I = tab[i][2], K = tab[i][3];
    int I4 = (I + 3) / 4;
    O_[idx] = O; I_[idx] = I; K_[idx] = K; I4_[idx] = I4;
    wT[idx] = (float*)alloc((size_t)K * I4 * O * 4 * 4);
  }

  int* map0 = (int*)alloc(524288 * 4);
  int* list0 = (int*)alloc((size_t)CAP0 * 4);
  int* map1 = (int*)alloc(65536 * 4);
  int* list1 = (int*)alloc(65536 * 4);
  int* map2 = (int*)alloc(8192 * 4);
  int* list2 = (int*)alloc(8192 * 4);
  int* map3 = (int*)alloc(1024 * 4);
  int* list3 = (int*)alloc(1024 * 4);
  int* map4 = (int*)alloc(128 * 4);
  int* list4 = (int*)alloc(128 * 4);
  int* bcnt = (int*)alloc(1024 * 4);
  int* cnts = (int*)alloc(32 * 4);
  float* stats = (float*)alloc(32 * 1024 * 4);
  float* zrow = (float*)alloc(256 * 4);
  float* G0 = (float*)alloc((size_t)CAP0 * 4 * 4);
  float* F0a = (float*)alloc((size_t)CAP0 * 32 * 4);
  float* F0b = (float*)alloc((size_t)CAP0 * 32 * 4);
  float *L1R[4], *L2R[4], *L3R[4], *L4R[4];
  for (int i = 0; i < 4; i++) L1R[i] = (float*)alloc((size_t)CAP1 * 32 * 4);
  for (int i = 0; i < 4; i++) L2R[i] = (float*)alloc((size_t)CAP2 * 64 * 4);
  for (int i = 0; i < 4; i++) L3R[i] = (float*)alloc((size_t)CAP3 * 128 * 4);
  for (int i = 0; i < 4; i++) L4R[i] = (float*)alloc((size_t)CAP4 * 256 * 4);

  hipMemsetAsync(cnts, 0, 32 * 4, stream);
  hipMemsetAsync(stats, 0, 32 * 1024 * 4, stream);
  hipMemsetAsync(zrow, 0, 256 * 4, stream);
  hipMemsetAsync(d_out, 0, (size_t)out_size * 4, stream);

  for (int idx = 2; idx <= 26; idx++) {
    long tot = (long)K_[idx] * I4_[idx] * O_[idx] * 4;
    wtr4_k<<<gup(tot), BLK, 0, stream>>>((const float*)d_in[idx], wT[idx],
                                         O_[idx], I_[idx], K_[idx], I4_[idx]);
  }

  int slot = 0;
  // ---- level 0 ----
  cnt_k<<<512, 1024, 0, stream>>>(mask0, nullptr, bcnt, 262144, 64, 64, 0, 524288);
  scan_k<<<1, 1024, 0, stream>>>(bcnt, 512, cnts + 0);
  emit_k<<<512, 1024, 0, stream>>>(mask0, nullptr, bcnt, map0, list0, 262144, 64, 64, 0, 524288);
  gather0_k<<<gup((long)CAP0 * 4), BLK, 0, stream>>>(feats, list0, cnts + 0, G0, 262144);

  int g0 = (CAP0 + 127) / 128;  // VT=128 for COUT=32
  int r0 = gup((long)CAP0 * 32); if (r0 > 1024) r0 = 1024;
  int a0 = gup((long)CAP0 * 32);

  conv3_t<4, 32, 8, 1><<<g0, 256, 0, stream>>>(G0, wT[2], F0a, list0, map0, cnts + 0, zrow, 64, 64, 64);
  float* sl = stats + (slot++) * 1024;
  bnred_k<32><<<r0, BLK, 0, stream>>>(F0a, cnts + 0, sl);
  bnapp_k<<<a0, BLK, 0, stream>>>(F0a, nullptr, sl, nullptr, cnts + 0, F0a, 31, 0);

  conv3_t<32, 32, 8, 1><<<g0, 256, 0, stream>>>(F0a, wT[3], F0b, list0, map0, cnts + 0, zrow, 64, 64, 64);
  sl = stats + (slot++) * 1024;
  bnred_k<32><<<r0, BLK, 0, stream>>>(F0b, cnts + 0, sl);
  bnapp_k<<<a0, BLK, 0, stream>>>(F0b, nullptr, sl, nullptr, cnts + 0, F0b, 31, 0);

  // ---- stages ----
  stage_h<32, 32, 1, 1>(F0b, wT[4], wT[5], wT[6], nullptr, wT[7], wT[8],
                        map0, map1, list1, cnts + 1, bcnt, 32, 32, 32, CAP1,
                        L1R[0], L1R[1], L1R[2], L1R[3], zrow, stats, slot, stream);
  stage_h<32, 64, 4, 2>(L1R[3], wT[9], wT[10], wT[11], wT[12], wT[13], wT[14],
                        map1, map2, list2, cnts + 2, bcnt, 16, 16, 16, CAP2,
                        L2R[0], L2R[1], L2R[2], L2R[3], zrow, stats, slot, stream);
  stage_h<64, 128, 8, 8>(L2R[3], wT[15], wT[16], wT[17], wT[18], wT[19], wT[20],
                         map2, map3, list3, cnts + 3, bcnt, 8, 8, 8, CAP3,
                         L3R[0], L3R[1], L3R[2], L3R[3], zrow, stats, slot, stream);
  stage_h<128, 256, 8, 27>(L3R[3], wT[21], wT[22], wT[23], wT[24], wT[25], wT[26],
                           map3, map4, list4, cnts + 4, bcnt, 4, 4, 4, CAP4,
                           L4R[0], L4R[1], L4R[2], L4R[3], zrow, stats, slot, stream);

  scatter_k<<<gup((long)CAP4 * 256), BLK, 0, stream>>>(L4R[3], list4, cnts + 4,
                                                      (float*)d_out, 64);
}